// Round 3
// baseline (476.954 us; speedup 1.0000x reference)
//
#include <hip/hip_runtime.h>

// x: (8,1,1024,1024) f32, y: (8,12,1024,1024) f32, out: scalar f32
// loss = mean(|gather(y) - x|), gather per 4x4 pixel-shuffle cell:
//   c = (H%4)*4 + (W%4)
//   pred = y[b, CH[c], (H&~3)+RO[c], W]        (CO[c] == W%4 always)
// Includes the reference's _PERM[15]=5 bug: c=15 -> (ch=4, ro=0).
//
// R1: removed same-address atomics (-55us: ~6.7ns/atomic x 8192).
// R2: 4 quads/thread (batch-stride: k -> b+2k, addresses differ by constant),
//     2048 blocks, 2048 partials. Kernel-side HBM floor ~26us (158 MB).

#define NB 2048

__global__ __launch_bounds__(256) void loss_partial_kernel(
        const float* __restrict__ x, const float* __restrict__ y,
        float* __restrict__ partial) {
    // nibble c of these packs = CH[c] / RO[c]
    const unsigned long long CH_PACK = 0x49A85241A7964130ULL;
    const unsigned long long RO_PACK = 0x0333222211110000ULL;

    unsigned t = blockIdx.x * 256u + threadIdx.x;   // quad id, 512K threads

    unsigned q    = t & 255u;          // quad index within row (W/4)
    unsigned hrow = (t >> 8) & 1023u;  // H (block-uniform)
    unsigned b0   = t >> 18;           // base batch: 0 or 1
    unsigned w4   = q << 2;            // W base

    unsigned rbase = hrow & ~3u;
    unsigned cbase = (hrow & 3u) << 2;

    // Per-j channel/row-offset (block-uniform -> scalar regs)
    unsigned ch[4], ro[4];
#pragma unroll
    for (int j = 0; j < 4; ++j) {
        unsigned c = cbase + (unsigned)j;
        ch[j] = (unsigned)(CH_PACK >> (4u * c)) & 0xFu;
        ro[j] = (unsigned)(RO_PACK >> (4u * c)) & 0xFu;
    }

    unsigned xoff = (((b0 << 10) | hrow) << 10) + w4;
    unsigned yoff[4];
#pragma unroll
    for (int j = 0; j < 4; ++j)
        yoff[j] = ((((b0 * 12u + ch[j]) << 10) + (rbase + ro[j])) << 10)
                  + (w4 + (unsigned)j);

    float acc = 0.0f;
#pragma unroll
    for (int k = 0; k < 4; ++k) {   // batches b0, b0+2, b0+4, b0+6
        const float4 xv = *reinterpret_cast<const float4*>(
            x + xoff + (unsigned)k * (2u << 20));
        float p0 = y[yoff[0] + (unsigned)k * (24u << 20)];
        float p1 = y[yoff[1] + (unsigned)k * (24u << 20)];
        float p2 = y[yoff[2] + (unsigned)k * (24u << 20)];
        float p3 = y[yoff[3] + (unsigned)k * (24u << 20)];
        acc += fabsf(p0 - xv.x) + fabsf(p1 - xv.y)
             + fabsf(p2 - xv.z) + fabsf(p3 - xv.w);
    }

    // wave-64 shuffle reduction
#pragma unroll
    for (int off = 32; off > 0; off >>= 1)
        acc += __shfl_down(acc, off, 64);

    __shared__ float smem[4];
    unsigned lane = threadIdx.x & 63u;
    unsigned wid  = threadIdx.x >> 6;
    if (lane == 0) smem[wid] = acc;
    __syncthreads();

    if (threadIdx.x == 0)
        partial[blockIdx.x] = (smem[0] + smem[1]) + (smem[2] + smem[3]);
}

__global__ __launch_bounds__(512) void final_reduce_kernel(
        const float* __restrict__ partial, float* __restrict__ out) {
    unsigned t = threadIdx.x;  // 0..511, 2048 partials = 512 float4
    const float4* p4 = reinterpret_cast<const float4*>(partial);
    float4 a = p4[t];
    float acc = (a.x + a.y) + (a.z + a.w);

#pragma unroll
    for (int off = 32; off > 0; off >>= 1)
        acc += __shfl_down(acc, off, 64);

    __shared__ float smem[8];
    unsigned lane = t & 63u;
    unsigned wid  = t >> 6;
    if (lane == 0) smem[wid] = acc;
    __syncthreads();

    if (t == 0) {
        float s = 0.0f;
#pragma unroll
        for (int i = 0; i < 8; ++i) s += smem[i];
        *out = s * (1.0f / 8388608.0f);
    }
}

extern "C" void kernel_launch(void* const* d_in, const int* in_sizes, int n_in,
                              void* d_out, int out_size, void* d_ws, size_t ws_size,
                              hipStream_t stream) {
    const float* x = (const float*)d_in[0];
    const float* y = (const float*)d_in[1];
    float* out     = (float*)d_out;
    float* partial = (float*)d_ws;   // 2048 floats = 8 KB

    hipLaunchKernelGGL(loss_partial_kernel, dim3(NB), dim3(256), 0, stream,
                       x, y, partial);
    hipLaunchKernelGGL(final_reduce_kernel, dim3(1), dim3(512), 0, stream,
                       partial, out);
}